// Round 9
// baseline (146.956 us; speedup 1.0000x reference)
//
#include <hip/hip_runtime.h>

// MHSA: B=2, T=2048, C=1024, H=16, hd=64. Inputs f32, output f32.
// cvt(all->bf16) -> QKV GEMM (XCD-swizzled; scatter Q*0.125*log2e, K, V^T)
// -> flash attn (swapped QK^T; sigma-permuted K rows => P in registers;
// 32 q/wave; defer-max; exp2; bh-grouped XCD remap) -> proj GEMM (f32 out).

typedef __bf16 bf16x4 __attribute__((ext_vector_type(4)));
typedef __bf16 bf16x8 __attribute__((ext_vector_type(8)));
typedef float  f32x4  __attribute__((ext_vector_type(4)));

#define AS1(p) ((const __attribute__((address_space(1))) void*)(p))
#define AS3(p) ((__attribute__((address_space(3))) void*)(p))

// ---------------------------------------------------------------------------
__global__ __launch_bounds__(256)
void cvt_all(const float* __restrict__ a, const float* __restrict__ b,
             const float* __restrict__ c, __bf16* __restrict__ oa,
             __bf16* __restrict__ ob, __bf16* __restrict__ oc,
             int na, int nb, int nc)
{
    const int total = (na + nb + nc) >> 2;
    const int stride = gridDim.x * blockDim.x;
    for (int i4 = blockIdx.x * blockDim.x + threadIdx.x; i4 < total; i4 += stride) {
        int i = i4 << 2;
        const float* src; __bf16* dst;
        if (i < na)               { src = a + i;             dst = oa + i; }
        else if (i < na + nb)     { src = b + (i - na);      dst = ob + (i - na); }
        else                      { src = c + (i - na - nb); dst = oc + (i - na - nb); }
        const float4 v = *(const float4*)src;
        bf16x4 o = { (__bf16)v.x, (__bf16)v.y, (__bf16)v.z, (__bf16)v.w };
        *(bf16x4*)dst = o;
    }
}

// ---------------------------------------------------------------------------
// GEMM out[m][n] = sum_k A[m][k]*W[n][k] + bias[n]. 128x128 tile, BK=64.
// XCD-bijective block swizzle. MODE 0: QKV scatter epilogue. MODE 1: f32 out.
// ---------------------------------------------------------------------------
template<int MODE>
__global__ __launch_bounds__(256)
void gemm_bt(const __bf16* __restrict__ A, const __bf16* __restrict__ W,
             const float* __restrict__ bias, int M, int N, int K,
             __bf16* __restrict__ O0, __bf16* __restrict__ O1,
             __bf16* __restrict__ O2, float* __restrict__ Of)
{
    __shared__ __bf16 sA[128 * 64];
    __shared__ __bf16 sB[128 * 64];
    const int tid  = threadIdx.x;
    const int w    = tid >> 6, lane = tid & 63;
    const int g    = lane >> 4, r16 = lane & 15;
    const int lin  = blockIdx.y * gridDim.x + blockIdx.x;
    const int per  = (gridDim.x * gridDim.y) >> 3;
    const int nlin = (lin & 7) * per + (lin >> 3);
    const int tM   = (nlin / gridDim.x) * 128, tN = (nlin % gridDim.x) * 128;
    const int wr   = w >> 1, wc = w & 1;
    const int crow = lane >> 3;
    const int ccol = (lane & 7) * 8;

    f32x4 acc[4][4] = {};

    for (int k0 = 0; k0 < K; k0 += 64) {
#pragma unroll
        for (int c = w; c < 16; c += 4) {
            const __bf16* ga = A + (size_t)(tM + c * 8 + crow) * K + k0 + ccol;
            __builtin_amdgcn_global_load_lds(AS1(ga), AS3(&sA[c * 8 * 64]), 16, 0, 0);
            const __bf16* gb = W + (size_t)(tN + c * 8 + crow) * K + k0 + ccol;
            __builtin_amdgcn_global_load_lds(AS1(gb), AS3(&sB[c * 8 * 64]), 16, 0, 0);
        }
        __syncthreads();
#pragma unroll
        for (int kk = 0; kk < 2; ++kk) {
            bf16x8 a[4], b[4];
#pragma unroll
            for (int mf = 0; mf < 4; ++mf)
                a[mf] = *(const bf16x8*)&sA[(wr * 64 + mf * 16 + r16) * 64 + kk * 32 + g * 8];
#pragma unroll
            for (int nf = 0; nf < 4; ++nf)
                b[nf] = *(const bf16x8*)&sB[(wc * 64 + nf * 16 + r16) * 64 + kk * 32 + g * 8];
#pragma unroll
            for (int mf = 0; mf < 4; ++mf)
#pragma unroll
                for (int nf = 0; nf < 4; ++nf)
                    acc[mf][nf] = __builtin_amdgcn_mfma_f32_16x16x32_bf16(
                        a[mf], b[nf], acc[mf][nf], 0, 0, 0);
        }
        __syncthreads();
    }

#pragma unroll
    for (int mf = 0; mf < 4; ++mf) {
#pragma unroll
        for (int nf = 0; nf < 4; ++nf) {
#pragma unroll
            for (int reg = 0; reg < 4; ++reg) {
                const int row = tM + wr * 64 + mf * 16 + g * 4 + reg;
                const int col = tN + wc * 64 + nf * 16 + r16;
                float v = acc[mf][nf][reg] + bias[col];
                if (MODE == 0) {
                    const int h = col / 192, j = col % 192;
                    const int b = row >> 11, t = row & 2047;
                    const size_t bh = (size_t)(b * 16 + h);
                    if (j < 64)   // Q: 0.125 * log2(e) -> exp2-domain softmax
                        O0[(bh * 2048 + t) * 64 + j] = (__bf16)(v * 0.18033688011112042f);
                    else if (j < 128)
                        O1[(bh * 2048 + t) * 64 + (j - 64)] = (__bf16)v;
                    else
                        O2[(bh * 64 + (j - 128)) * 2048 + t] = (__bf16)v;
                } else {
                    Of[(size_t)row * N + col] = v;
                }
            }
        }
    }
}

// ---------------------------------------------------------------------------
// Flash attention, swapped QK^T, 32 q/wave, 4 waves/block (128 q), grid 512,
// bh-grouped XCD remap (4 heads/XCD -> K/V L2-resident). K/V^T staged in LDS
// (dbuf, swizzled). K A-fragment rows sigma-permuted so P stays in registers
// (zero cross-lane, zero LDS round-trip). Softmax lane-local, exp2 domain,
// defer-max THR=8. kb/vb LDS reads shared by both q sub-blocks (h=0,1):
// halves LDS-pipe bytes per q vs 16q/wave.
// ---------------------------------------------------------------------------
__global__ __launch_bounds__(256, 2)
void attn(const __bf16* __restrict__ Q, const __bf16* __restrict__ K,
          const __bf16* __restrict__ V, __bf16* __restrict__ O)
{
    __shared__ __bf16 sK[2][64 * 64];   // 8 KB each
    __shared__ __bf16 sV[2][64 * 64];   // V^T tile [d][kv]

    const int tid = threadIdx.x;
    const int w   = tid >> 6, lane = tid & 63;
    const int g   = lane >> 4, r16 = lane & 15;
    // bijective remap of 512 ids: XCD c serves bh in {c, c+8, c+16, c+24}
    const int m      = blockIdx.x;
    const int within = m >> 3;
    const int bh     = (m & 7) + ((within >> 4) << 3);
    const int qb     = within & 15;
    const int q0     = qb * 128 + w * 32;
    const __bf16* Qp = Q + (size_t)bh * 2048 * 64;
    const __bf16* Kp = K + (size_t)bh * 2048 * 64;
    const __bf16* Vp = V + (size_t)bh * 64 * 2048;

    const int srow  = lane >> 3;
    const int scolV = 8 * ((lane & 7) ^ srow);                             // s = row&7
    const int scolK = 8 * ((lane & 7) ^ ((srow & 3) | ((w & 1) << 2)));    // s = (row&3)|((row>>3&1)<<2)
    const int swzK  = ((r16 & 3) | (((r16 >> 2) & 1) << 2)) << 4;
    const int swzV  = (r16 & 7) << 4;

    // Q fragments (B-operand): lane r16 = q, k = d; h = q sub-block
    bf16x8 qa[2][2];
#pragma unroll
    for (int h = 0; h < 2; ++h)
#pragma unroll
        for (int kk = 0; kk < 2; ++kk)
            qa[h][kk] = *(const bf16x8*)(Qp + (size_t)(q0 + h * 16 + r16) * 64 + kk * 32 + g * 8);

    f32x4 o[2][4] = {};
    float mrun[2] = { -1e30f, -1e30f }, lrun[2] = { 0.f, 0.f };

    // ---- stage tile 0 ----
#pragma unroll
    for (int r = 0; r < 2; ++r) {
        const int ldsb = r * 4096 + w * 1024;
        const int row  = r * 32 + w * 8 + srow;
        __builtin_amdgcn_global_load_lds(AS1(Kp + (size_t)row * 64 + scolK),
                                         AS3((char*)&sK[0][0] + ldsb), 16, 0, 0);
        __builtin_amdgcn_global_load_lds(AS1(Vp + (size_t)row * 2048 + scolV),
                                         AS3((char*)&sV[0][0] + ldsb), 16, 0, 0);
    }
    __syncthreads();

    for (int t = 0; t < 32; ++t) {
        const int cur = t & 1;
        if (t < 31) {
            const int kvn = (t + 1) * 64;
#pragma unroll
            for (int r = 0; r < 2; ++r) {
                const int ldsb = r * 4096 + w * 1024;
                const int row  = r * 32 + w * 8 + srow;
                __builtin_amdgcn_global_load_lds(AS1(Kp + (size_t)(kvn + row) * 64 + scolK),
                                                 AS3((char*)&sK[cur ^ 1][0] + ldsb), 16, 0, 0);
                __builtin_amdgcn_global_load_lds(AS1(Vp + (size_t)row * 2048 + kvn + scolV),
                                                 AS3((char*)&sV[cur ^ 1][0] + ldsb), 16, 0, 0);
            }
        }
        // ---- S_T[kv][q] = K Q^T with sigma-permuted K rows (shared kb) ----
        bf16x8 kb[4][2];
#pragma unroll
        for (int nf = 0; nf < 4; ++nf) {
            const int row = ((nf >> 1) << 5) + ((r16 >> 2) << 3) + ((nf & 1) << 2) + (r16 & 3);
#pragma unroll
            for (int kk = 0; kk < 2; ++kk)
                kb[nf][kk] = *(const bf16x8*)((const char*)&sK[cur][0] + row * 128
                                              + ((kk * 64 + g * 16) ^ swzK));
        }
        f32x4 S[2][4];
        __builtin_amdgcn_s_setprio(1);
#pragma unroll
        for (int h = 0; h < 2; ++h)
#pragma unroll
            for (int nf = 0; nf < 4; ++nf) {
                f32x4 s = {};
                s = __builtin_amdgcn_mfma_f32_16x16x32_bf16(kb[nf][0], qa[h][0], s, 0, 0, 0);
                s = __builtin_amdgcn_mfma_f32_16x16x32_bf16(kb[nf][1], qa[h][1], s, 0, 0, 0);
                S[h][nf] = s;
            }
        __builtin_amdgcn_s_setprio(0);
        // ---- softmax (exp2 domain), lane-local + 2 shfls, defer-max ----
        float rm[2];
#pragma unroll
        for (int h = 0; h < 2; ++h) {
            float m0 = fmaxf(fmaxf(S[h][0][0], S[h][0][1]), fmaxf(S[h][0][2], S[h][0][3]));
#pragma unroll
            for (int nf = 1; nf < 4; ++nf)
                m0 = fmaxf(m0, fmaxf(fmaxf(S[h][nf][0], S[h][nf][1]),
                                     fmaxf(S[h][nf][2], S[h][nf][3])));
            m0 = fmaxf(m0, __shfl_xor(m0, 16));
            m0 = fmaxf(m0, __shfl_xor(m0, 32));
            rm[h] = m0;
        }
        if (!__all(rm[0] <= mrun[0] + 8.f && rm[1] <= mrun[1] + 8.f)) {
#pragma unroll
            for (int h = 0; h < 2; ++h) {
                const float mn = fmaxf(mrun[h], rm[h]);
                const float al = exp2f(mrun[h] - mn);
#pragma unroll
                for (int df = 0; df < 4; ++df)
#pragma unroll
                    for (int reg = 0; reg < 4; ++reg) o[h][df][reg] *= al;
                lrun[h] *= al;
                mrun[h] = mn;
            }
        }
        bf16x8 pb[2][2];
#pragma unroll
        for (int h = 0; h < 2; ++h) {
            float ps = 0.f;
#pragma unroll
            for (int nf = 0; nf < 4; ++nf)
#pragma unroll
                for (int reg = 0; reg < 4; ++reg) {
                    const float p = exp2f(S[h][nf][reg] - mrun[h]);
                    S[h][nf][reg] = p;
                    ps += p;
                }
            lrun[h] += ps;
            // P register-resident: pb[h][kk][j] = S[h][kk*2+(j>>2)][j&3]
#pragma unroll
            for (int kk = 0; kk < 2; ++kk) {
                bf16x8 tpk;
                tpk[0] = (__bf16)S[h][kk * 2][0];     tpk[1] = (__bf16)S[h][kk * 2][1];
                tpk[2] = (__bf16)S[h][kk * 2][2];     tpk[3] = (__bf16)S[h][kk * 2][3];
                tpk[4] = (__bf16)S[h][kk * 2 + 1][0]; tpk[5] = (__bf16)S[h][kk * 2 + 1][1];
                tpk[6] = (__bf16)S[h][kk * 2 + 1][2]; tpk[7] = (__bf16)S[h][kk * 2 + 1][3];
                pb[h][kk] = tpk;
            }
        }
        // ---- O_T += V_T P_T (vb shared by both h) ----
        __builtin_amdgcn_s_setprio(1);
#pragma unroll
        for (int kk = 0; kk < 2; ++kk)
#pragma unroll
            for (int df = 0; df < 4; ++df) {
                const int row = df * 16 + r16;
                bf16x8 vb = *(const bf16x8*)((const char*)&sV[cur][0] + row * 128
                                             + ((kk * 64 + g * 16) ^ swzV));
#pragma unroll
                for (int h = 0; h < 2; ++h)
                    o[h][df] = __builtin_amdgcn_mfma_f32_16x16x32_bf16(vb, pb[h][kk], o[h][df], 0, 0, 0);
            }
        __builtin_amdgcn_s_setprio(0);
        __syncthreads();
    }

    // ---- finish denominators and store O_T -> Os[token][c] ----
#pragma unroll
    for (int h = 0; h < 2; ++h) {
        float l = lrun[h];
        l += __shfl_xor(l, 16);
        l += __shfl_xor(l, 32);
        const float inv = 1.f / l;
        const size_t token = (size_t)(bh >> 4) * 2048 + q0 + h * 16 + r16;
#pragma unroll
        for (int df = 0; df < 4; ++df) {
            bf16x4 ov = { (__bf16)(o[h][df][0] * inv), (__bf16)(o[h][df][1] * inv),
                          (__bf16)(o[h][df][2] * inv), (__bf16)(o[h][df][3] * inv) };
            *(bf16x4*)(O + token * 1024 + (bh & 15) * 64 + df * 16 + g * 4) = ov;
        }
    }
}

// ---------------------------------------------------------------------------
extern "C" void kernel_launch(void* const* d_in, const int* in_sizes, int n_in,
                              void* d_out, int out_size, void* d_ws, size_t ws_size,
                              hipStream_t stream)
{
    const float* x     = (const float*)d_in[0];
    const float* Wqkv  = (const float*)d_in[1];
    const float* bqkv  = (const float*)d_in[2];
    const float* Wproj = (const float*)d_in[3];
    const float* bproj = (const float*)d_in[4];
    float* out = (float*)d_out;

    const size_t NX   = (size_t)4096 * 1024;
    const size_t NWQ  = (size_t)3072 * 1024;
    const size_t NWP  = (size_t)1024 * 1024;

    __bf16* xb  = (__bf16*)d_ws;
    __bf16* Wqb = xb  + NX;
    __bf16* Wpb = Wqb + NWQ;
    __bf16* Qs  = Wpb + NWP;           // (B,H,T,64), scaled 0.125*log2e
    __bf16* Ks  = Qs  + NX;            // (B,H,T,64)
    __bf16* Vt  = Ks  + NX;            // (B,H,64,T)
    __bf16* Os  = Vt  + NX;            // (B*T, C)

    cvt_all<<<dim3(2048), dim3(256), 0, stream>>>(x, Wqkv, Wproj, xb, Wqb, Wpb,
                                                  (int)NX, (int)NWQ, (int)NWP);
    gemm_bt<0><<<dim3(24, 32), dim3(256), 0, stream>>>(xb, Wqb, bqkv, 4096, 3072, 1024, Qs, Ks, Vt, nullptr);
    attn<<<dim3(512), dim3(256), 0, stream>>>(Qs, Ks, Vt, Os);
    gemm_bt<1><<<dim3(8, 32), dim3(256), 0, stream>>>(Os, Wpb, bproj, 4096, 1024, 1024, nullptr, nullptr, nullptr, out);
}

// Round 10
// 138.388 us; speedup vs baseline: 1.0619x; 1.0619x over previous
//
#include <hip/hip_runtime.h>

// MHSA: B=2, T=2048, C=1024, H=16, hd=64. Inputs f32, output f32.
// cvt(all->bf16) -> QKV GEMM (XCD-swizzled; scatter Q*0.125*log2e, K, V^T)
// -> flash attn (swapped QK^T; sigma-permuted K rows => P in registers;
// C-init=-mrun kills subs; ones-MFMA denominator kills adds+final reduce;
// shfl-free defer-max; bh-grouped XCD remap) -> proj GEMM (f32 out).

typedef __bf16 bf16x4 __attribute__((ext_vector_type(4)));
typedef __bf16 bf16x8 __attribute__((ext_vector_type(8)));
typedef float  f32x4  __attribute__((ext_vector_type(4)));

#define AS1(p) ((const __attribute__((address_space(1))) void*)(p))
#define AS3(p) ((__attribute__((address_space(3))) void*)(p))

// ---------------------------------------------------------------------------
__global__ __launch_bounds__(256)
void cvt_all(const float* __restrict__ a, const float* __restrict__ b,
             const float* __restrict__ c, __bf16* __restrict__ oa,
             __bf16* __restrict__ ob, __bf16* __restrict__ oc,
             int na, int nb, int nc)
{
    const int total = (na + nb + nc) >> 2;
    const int stride = gridDim.x * blockDim.x;
    for (int i4 = blockIdx.x * blockDim.x + threadIdx.x; i4 < total; i4 += stride) {
        int i = i4 << 2;
        const float* src; __bf16* dst;
        if (i < na)               { src = a + i;             dst = oa + i; }
        else if (i < na + nb)     { src = b + (i - na);      dst = ob + (i - na); }
        else                      { src = c + (i - na - nb); dst = oc + (i - na - nb); }
        const float4 v = *(const float4*)src;
        bf16x4 o = { (__bf16)v.x, (__bf16)v.y, (__bf16)v.z, (__bf16)v.w };
        *(bf16x4*)dst = o;
    }
}

// ---------------------------------------------------------------------------
// GEMM out[m][n] = sum_k A[m][k]*W[n][k] + bias[n]. 128x128 tile, BK=64.
// XCD-bijective block swizzle. MODE 0: QKV scatter epilogue. MODE 1: f32 out.
// ---------------------------------------------------------------------------
template<int MODE>
__global__ __launch_bounds__(256)
void gemm_bt(const __bf16* __restrict__ A, const __bf16* __restrict__ W,
             const float* __restrict__ bias, int M, int N, int K,
             __bf16* __restrict__ O0, __bf16* __restrict__ O1,
             __bf16* __restrict__ O2, float* __restrict__ Of)
{
    __shared__ __bf16 sA[128 * 64];
    __shared__ __bf16 sB[128 * 64];
    const int tid  = threadIdx.x;
    const int w    = tid >> 6, lane = tid & 63;
    const int g    = lane >> 4, r16 = lane & 15;
    const int lin  = blockIdx.y * gridDim.x + blockIdx.x;
    const int per  = (gridDim.x * gridDim.y) >> 3;
    const int nlin = (lin & 7) * per + (lin >> 3);
    const int tM   = (nlin / gridDim.x) * 128, tN = (nlin % gridDim.x) * 128;
    const int wr   = w >> 1, wc = w & 1;
    const int crow = lane >> 3;
    const int ccol = (lane & 7) * 8;

    f32x4 acc[4][4] = {};

    for (int k0 = 0; k0 < K; k0 += 64) {
#pragma unroll
        for (int c = w; c < 16; c += 4) {
            const __bf16* ga = A + (size_t)(tM + c * 8 + crow) * K + k0 + ccol;
            __builtin_amdgcn_global_load_lds(AS1(ga), AS3(&sA[c * 8 * 64]), 16, 0, 0);
            const __bf16* gb = W + (size_t)(tN + c * 8 + crow) * K + k0 + ccol;
            __builtin_amdgcn_global_load_lds(AS1(gb), AS3(&sB[c * 8 * 64]), 16, 0, 0);
        }
        __syncthreads();
#pragma unroll
        for (int kk = 0; kk < 2; ++kk) {
            bf16x8 a[4], b[4];
#pragma unroll
            for (int mf = 0; mf < 4; ++mf)
                a[mf] = *(const bf16x8*)&sA[(wr * 64 + mf * 16 + r16) * 64 + kk * 32 + g * 8];
#pragma unroll
            for (int nf = 0; nf < 4; ++nf)
                b[nf] = *(const bf16x8*)&sB[(wc * 64 + nf * 16 + r16) * 64 + kk * 32 + g * 8];
#pragma unroll
            for (int mf = 0; mf < 4; ++mf)
#pragma unroll
                for (int nf = 0; nf < 4; ++nf)
                    acc[mf][nf] = __builtin_amdgcn_mfma_f32_16x16x32_bf16(
                        a[mf], b[nf], acc[mf][nf], 0, 0, 0);
        }
        __syncthreads();
    }

#pragma unroll
    for (int mf = 0; mf < 4; ++mf) {
#pragma unroll
        for (int nf = 0; nf < 4; ++nf) {
#pragma unroll
            for (int reg = 0; reg < 4; ++reg) {
                const int row = tM + wr * 64 + mf * 16 + g * 4 + reg;
                const int col = tN + wc * 64 + nf * 16 + r16;
                float v = acc[mf][nf][reg] + bias[col];
                if (MODE == 0) {
                    const int h = col / 192, j = col % 192;
                    const int b = row >> 11, t = row & 2047;
                    const size_t bh = (size_t)(b * 16 + h);
                    if (j < 64)   // Q: 0.125 * log2(e) -> exp2-domain softmax
                        O0[(bh * 2048 + t) * 64 + j] = (__bf16)(v * 0.18033688011112042f);
                    else if (j < 128)
                        O1[(bh * 2048 + t) * 64 + (j - 64)] = (__bf16)v;
                    else
                        O2[(bh * 64 + (j - 128)) * 2048 + t] = (__bf16)v;
                } else {
                    Of[(size_t)row * N + col] = v;
                }
            }
        }
    }
}

// ---------------------------------------------------------------------------
// Flash attention, swapped QK^T, 16 q/wave, 4 waves/block, grid 1024,
// bh-grouped XCD remap. K/V^T staged in LDS (dbuf, swizzled); sigma-permuted
// K rows keep P in registers. Softmax v2: QK^T accumulator C-init = -mrun
// (no subs), denominator via ones-MFMA (no adds, no final reduce), defer-max
// with shfls only inside the rare rescale branch.
// ---------------------------------------------------------------------------
__global__ __launch_bounds__(256, 4)
void attn(const __bf16* __restrict__ Q, const __bf16* __restrict__ K,
          const __bf16* __restrict__ V, __bf16* __restrict__ O)
{
    __shared__ __bf16 sK[2][64 * 64];   // 8 KB each
    __shared__ __bf16 sV[2][64 * 64];   // V^T tile [d][kv]

    const int tid = threadIdx.x;
    const int w   = tid >> 6, lane = tid & 63;
    const int g   = lane >> 4, r16 = lane & 15;
    // bijective remap of the 1024 linear ids: each XCD gets 4 whole bh's
    const int m   = blockIdx.x + (blockIdx.y << 5) + (blockIdx.z << 9);
    const int bh  = (m & 7) + ((m >> 8) << 3);
    const int qb  = (m >> 3) & 31;
    const int q0  = qb * 64 + w * 16;
    const __bf16* Qp = Q + (size_t)bh * 2048 * 64;
    const __bf16* Kp = K + (size_t)bh * 2048 * 64;
    const __bf16* Vp = V + (size_t)bh * 64 * 2048;

    const int srow  = lane >> 3;
    const int scolV = 8 * ((lane & 7) ^ srow);                             // s = row&7
    const int scolK = 8 * ((lane & 7) ^ ((srow & 3) | ((w & 1) << 2)));    // s = (row&3)|((row>>3&1)<<2)
    const int swzK  = ((r16 & 3) | (((r16 >> 2) & 1) << 2)) << 4;
    const int swzV  = (r16 & 7) << 4;

    // Q fragments (B-operand): lane r16 = q, k = d
    bf16x8 qa[2];
#pragma unroll
    for (int kk = 0; kk < 2; ++kk)
        qa[kk] = *(const bf16x8*)(Qp + (size_t)(q0 + r16) * 64 + kk * 32 + g * 8);

    bf16x8 ones;
#pragma unroll
    for (int i = 0; i < 8; ++i) ones[i] = (__bf16)1.0f;

    f32x4 o[4] = {};
    f32x4 lsum = {};
    float mrun = 0.f;

    // ---- stage tile 0 ----
#pragma unroll
    for (int r = 0; r < 2; ++r) {
        const int ldsb = r * 4096 + w * 1024;
        const int row  = r * 32 + w * 8 + srow;
        __builtin_amdgcn_global_load_lds(AS1(Kp + (size_t)row * 64 + scolK),
                                         AS3((char*)&sK[0][0] + ldsb), 16, 0, 0);
        __builtin_amdgcn_global_load_lds(AS1(Vp + (size_t)row * 2048 + scolV),
                                         AS3((char*)&sV[0][0] + ldsb), 16, 0, 0);
    }
    __syncthreads();

    for (int t = 0; t < 32; ++t) {
        const int cur = t & 1;
        if (t < 31) {
            const int kvn = (t + 1) * 64;
#pragma unroll
            for (int r = 0; r < 2; ++r) {
                const int ldsb = r * 4096 + w * 1024;
                const int row  = r * 32 + w * 8 + srow;
                __builtin_amdgcn_global_load_lds(AS1(Kp + (size_t)(kvn + row) * 64 + scolK),
                                                 AS3((char*)&sK[cur ^ 1][0] + ldsb), 16, 0, 0);
                __builtin_amdgcn_global_load_lds(AS1(Vp + (size_t)row * 2048 + kvn + scolV),
                                                 AS3((char*)&sV[cur ^ 1][0] + ldsb), 16, 0, 0);
            }
        }
        // ---- S' = K Q^T - mrun (C-init), sigma-permuted K rows ----
        bf16x8 kb[4][2];
#pragma unroll
        for (int nf = 0; nf < 4; ++nf) {
            const int row = ((nf >> 1) << 5) + ((r16 >> 2) << 3) + ((nf & 1) << 2) + (r16 & 3);
#pragma unroll
            for (int kk = 0; kk < 2; ++kk)
                kb[nf][kk] = *(const bf16x8*)((const char*)&sK[cur][0] + row * 128
                                              + ((kk * 64 + g * 16) ^ swzK));
        }
        const f32x4 cinit = { -mrun, -mrun, -mrun, -mrun };
        f32x4 S[4];
        __builtin_amdgcn_s_setprio(1);
#pragma unroll
        for (int nf = 0; nf < 4; ++nf) {
            f32x4 s = __builtin_amdgcn_mfma_f32_16x16x32_bf16(kb[nf][0], qa[0], cinit, 0, 0, 0);
            S[nf]   = __builtin_amdgcn_mfma_f32_16x16x32_bf16(kb[nf][1], qa[1], s, 0, 0, 0);
        }
        __builtin_amdgcn_s_setprio(0);
        // ---- defer-max: shfl-free common path ----
        float rm = fmaxf(fmaxf(S[0][0], S[0][1]), fmaxf(S[0][2], S[0][3]));
#pragma unroll
        for (int nf = 1; nf < 4; ++nf)
            rm = fmaxf(rm, fmaxf(fmaxf(S[nf][0], S[nf][1]), fmaxf(S[nf][2], S[nf][3])));
        if (!__all(rm <= 8.f)) {
            rm = fmaxf(rm, __shfl_xor(rm, 16));
            rm = fmaxf(rm, __shfl_xor(rm, 32));
            const float delta = fmaxf(rm, 0.f);
            const float al = exp2f(-delta);
#pragma unroll
            for (int df = 0; df < 4; ++df)
#pragma unroll
                for (int reg = 0; reg < 4; ++reg) o[df][reg] *= al;
#pragma unroll
            for (int reg = 0; reg < 4; ++reg) lsum[reg] *= al;
            mrun += delta;
#pragma unroll
            for (int nf = 0; nf < 4; ++nf)
#pragma unroll
                for (int reg = 0; reg < 4; ++reg) S[nf][reg] -= delta;
        }
        // ---- P = exp2(S'), packed straight into PV B-fragments ----
        bf16x8 pb[2];
#pragma unroll
        for (int kk = 0; kk < 2; ++kk) {
            bf16x8 tpk;
            tpk[0] = (__bf16)exp2f(S[kk * 2][0]);     tpk[1] = (__bf16)exp2f(S[kk * 2][1]);
            tpk[2] = (__bf16)exp2f(S[kk * 2][2]);     tpk[3] = (__bf16)exp2f(S[kk * 2][3]);
            tpk[4] = (__bf16)exp2f(S[kk * 2 + 1][0]); tpk[5] = (__bf16)exp2f(S[kk * 2 + 1][1]);
            tpk[6] = (__bf16)exp2f(S[kk * 2 + 1][2]); tpk[7] = (__bf16)exp2f(S[kk * 2 + 1][3]);
            pb[kk] = tpk;
        }
        // ---- O_T += V_T P_T ; denominator via ones-MFMA ----
        __builtin_amdgcn_s_setprio(1);
        lsum = __builtin_amdgcn_mfma_f32_16x16x32_bf16(ones, pb[0], lsum, 0, 0, 0);
        lsum = __builtin_amdgcn_mfma_f32_16x16x32_bf16(ones, pb[1], lsum, 0, 0, 0);
#pragma unroll
        for (int kk = 0; kk < 2; ++kk)
#pragma unroll
            for (int df = 0; df < 4; ++df) {
                const int row = df * 16 + r16;
                bf16x8 vb = *(const bf16x8*)((const char*)&sV[cur][0] + row * 128
                                             + ((kk * 64 + g * 16) ^ swzV));
                o[df] = __builtin_amdgcn_mfma_f32_16x16x32_bf16(vb, pb[kk], o[df], 0, 0, 0);
            }
        __builtin_amdgcn_s_setprio(0);
        __syncthreads();
    }

    // ---- store O_T -> Os[token][c] (lsum already the full denominator) ----
    const float inv = 1.f / lsum[0];
    const size_t token = (size_t)(bh >> 4) * 2048 + q0 + r16;
#pragma unroll
    for (int df = 0; df < 4; ++df) {
        bf16x4 ov = { (__bf16)(o[df][0] * inv), (__bf16)(o[df][1] * inv),
                      (__bf16)(o[df][2] * inv), (__bf16)(o[df][3] * inv) };
        *(bf16x4*)(O + token * 1024 + (bh & 15) * 64 + df * 16 + g * 4) = ov;
    }
}

// ---------------------------------------------------------------------------
extern "C" void kernel_launch(void* const* d_in, const int* in_sizes, int n_in,
                              void* d_out, int out_size, void* d_ws, size_t ws_size,
                              hipStream_t stream)
{
    const float* x     = (const float*)d_in[0];
    const float* Wqkv  = (const float*)d_in[1];
    const float* bqkv  = (const float*)d_in[2];
    const float* Wproj = (const float*)d_in[3];
    const float* bproj = (const float*)d_in[4];
    float* out = (float*)d_out;

    const size_t NX   = (size_t)4096 * 1024;
    const size_t NWQ  = (size_t)3072 * 1024;
    const size_t NWP  = (size_t)1024 * 1024;

    __bf16* xb  = (__bf16*)d_ws;
    __bf16* Wqb = xb  + NX;
    __bf16* Wpb = Wqb + NWQ;
    __bf16* Qs  = Wpb + NWP;           // (B,H,T,64), scaled 0.125*log2e
    __bf16* Ks  = Qs  + NX;            // (B,H,T,64)
    __bf16* Vt  = Ks  + NX;            // (B,H,64,T)
    __bf16* Os  = Vt  + NX;            // (B*T, C)

    cvt_all<<<dim3(2048), dim3(256), 0, stream>>>(x, Wqkv, Wproj, xb, Wqb, Wpb,
                                                  (int)NX, (int)NWQ, (int)NWP);
    gemm_bt<0><<<dim3(24, 32), dim3(256), 0, stream>>>(xb, Wqb, bqkv, 4096, 3072, 1024, Qs, Ks, Vt, nullptr);
    attn<<<dim3(32, 16, 2), dim3(256), 0, stream>>>(Qs, Ks, Vt, Os);
    gemm_bt<1><<<dim3(8, 32), dim3(256), 0, stream>>>(Os, Wpb, bproj, 4096, 1024, 1024, nullptr, nullptr, nullptr, out);
}

// Round 11
// 121.832 us; speedup vs baseline: 1.2062x; 1.1359x over previous
//
#include <hip/hip_runtime.h>

// MHSA: B=2, T=2048, C=1024, H=16, hd=64. Inputs f32, output f32.
// cvt(all->bf16) -> QKV GEMM (XCD-swizzled; scatter Q*0.125*log2e, K, V^T
// with packed V stores) -> flash attn (swapped QK^T; sigma-permuted K rows =>
// P in registers; C-init=-mrun; ones-MFMA denominator; raw v_exp_f32;
// strength-reduced staging; bh-grouped XCD remap) -> proj GEMM (f32 out).

typedef __bf16 bf16x4 __attribute__((ext_vector_type(4)));
typedef __bf16 bf16x8 __attribute__((ext_vector_type(8)));
typedef float  f32x4  __attribute__((ext_vector_type(4)));

#define AS1(p) ((const __attribute__((address_space(1))) void*)(p))
#define AS3(p) ((__attribute__((address_space(3))) void*)(p))

// ---------------------------------------------------------------------------
__global__ __launch_bounds__(256)
void cvt_all(const float* __restrict__ a, const float* __restrict__ b,
             const float* __restrict__ c, __bf16* __restrict__ oa,
             __bf16* __restrict__ ob, __bf16* __restrict__ oc,
             int na, int nb, int nc)
{
    const int total = (na + nb + nc) >> 2;
    const int stride = gridDim.x * blockDim.x;
    for (int i4 = blockIdx.x * blockDim.x + threadIdx.x; i4 < total; i4 += stride) {
        int i = i4 << 2;
        const float* src; __bf16* dst;
        if (i < na)               { src = a + i;             dst = oa + i; }
        else if (i < na + nb)     { src = b + (i - na);      dst = ob + (i - na); }
        else                      { src = c + (i - na - nb); dst = oc + (i - na - nb); }
        const float4 v = *(const float4*)src;
        bf16x4 o = { (__bf16)v.x, (__bf16)v.y, (__bf16)v.z, (__bf16)v.w };
        *(bf16x4*)dst = o;
    }
}

// ---------------------------------------------------------------------------
// GEMM out[m][n] = sum_k A[m][k]*W[n][k] + bias[n]. 128x128 tile, BK=64.
// XCD-bijective block swizzle. MODE 0: QKV scatter epilogue (packed V^T
// stores: the 4 acc regs are 4 consecutive t in one V^T row). MODE 1: f32.
// ---------------------------------------------------------------------------
template<int MODE>
__global__ __launch_bounds__(256)
void gemm_bt(const __bf16* __restrict__ A, const __bf16* __restrict__ W,
             const float* __restrict__ bias, int M, int N, int K,
             __bf16* __restrict__ O0, __bf16* __restrict__ O1,
             __bf16* __restrict__ O2, float* __restrict__ Of)
{
    __shared__ __bf16 sA[128 * 64];
    __shared__ __bf16 sB[128 * 64];
    const int tid  = threadIdx.x;
    const int w    = tid >> 6, lane = tid & 63;
    const int g    = lane >> 4, r16 = lane & 15;
    const int lin  = blockIdx.y * gridDim.x + blockIdx.x;
    const int per  = (gridDim.x * gridDim.y) >> 3;
    const int nlin = (lin & 7) * per + (lin >> 3);
    const int tM   = (nlin / gridDim.x) * 128, tN = (nlin % gridDim.x) * 128;
    const int wr   = w >> 1, wc = w & 1;
    const int crow = lane >> 3;
    const int ccol = (lane & 7) * 8;

    f32x4 acc[4][4] = {};

    for (int k0 = 0; k0 < K; k0 += 64) {
#pragma unroll
        for (int c = w; c < 16; c += 4) {
            const __bf16* ga = A + (size_t)(tM + c * 8 + crow) * K + k0 + ccol;
            __builtin_amdgcn_global_load_lds(AS1(ga), AS3(&sA[c * 8 * 64]), 16, 0, 0);
            const __bf16* gb = W + (size_t)(tN + c * 8 + crow) * K + k0 + ccol;
            __builtin_amdgcn_global_load_lds(AS1(gb), AS3(&sB[c * 8 * 64]), 16, 0, 0);
        }
        __syncthreads();
#pragma unroll
        for (int kk = 0; kk < 2; ++kk) {
            bf16x8 a[4], b[4];
#pragma unroll
            for (int mf = 0; mf < 4; ++mf)
                a[mf] = *(const bf16x8*)&sA[(wr * 64 + mf * 16 + r16) * 64 + kk * 32 + g * 8];
#pragma unroll
            for (int nf = 0; nf < 4; ++nf)
                b[nf] = *(const bf16x8*)&sB[(wc * 64 + nf * 16 + r16) * 64 + kk * 32 + g * 8];
#pragma unroll
            for (int mf = 0; mf < 4; ++mf)
#pragma unroll
                for (int nf = 0; nf < 4; ++nf)
                    acc[mf][nf] = __builtin_amdgcn_mfma_f32_16x16x32_bf16(
                        a[mf], b[nf], acc[mf][nf], 0, 0, 0);
        }
        __syncthreads();
    }

#pragma unroll
    for (int mf = 0; mf < 4; ++mf) {
#pragma unroll
        for (int nf = 0; nf < 4; ++nf) {
            if (MODE == 0) {
                const int col  = tN + wc * 64 + nf * 16 + r16;
                const int h    = col / 192, j = col % 192;
                const int rowb = tM + wr * 64 + mf * 16 + g * 4;   // +reg, no b/t wrap
                const int b    = rowb >> 11, t = rowb & 2047;
                const size_t bh = (size_t)(b * 16 + h);
                const float bs = bias[col];
                if (j >= 128) {
                    // V^T: 4 regs = 4 consecutive t in row (bh*64 + j-128)
                    bf16x4 pk = { (__bf16)(acc[mf][nf][0] + bs), (__bf16)(acc[mf][nf][1] + bs),
                                  (__bf16)(acc[mf][nf][2] + bs), (__bf16)(acc[mf][nf][3] + bs) };
                    *(bf16x4*)&O2[(bh * 64 + (j - 128)) * 2048 + t] = pk;
                } else if (j < 64) {
#pragma unroll
                    for (int reg = 0; reg < 4; ++reg)
                        O0[(bh * 2048 + t + reg) * 64 + j] =
                            (__bf16)((acc[mf][nf][reg] + bs) * 0.18033688011112042f);
                } else {
#pragma unroll
                    for (int reg = 0; reg < 4; ++reg)
                        O1[(bh * 2048 + t + reg) * 64 + (j - 64)] =
                            (__bf16)(acc[mf][nf][reg] + bs);
                }
            } else {
#pragma unroll
                for (int reg = 0; reg < 4; ++reg) {
                    const int row = tM + wr * 64 + mf * 16 + g * 4 + reg;
                    const int col = tN + wc * 64 + nf * 16 + r16;
                    Of[(size_t)row * N + col] = acc[mf][nf][reg] + bias[col];
                }
            }
        }
    }
}

// ---------------------------------------------------------------------------
// Flash attention, swapped QK^T, 16 q/wave, 4 waves/block, grid 1024,
// bh-grouped XCD remap. K/V^T staged in LDS (dbuf, swizzled); sigma-permuted
// K rows keep P in registers. C-init=-mrun, ones-MFMA denominator, raw
// v_exp_f32, strength-reduced staging pointers.
// ---------------------------------------------------------------------------
__global__ __launch_bounds__(256, 4)
void attn(const __bf16* __restrict__ Q, const __bf16* __restrict__ K,
          const __bf16* __restrict__ V, __bf16* __restrict__ O)
{
    __shared__ __bf16 sK[2][64 * 64];   // 8 KB each
    __shared__ __bf16 sV[2][64 * 64];   // V^T tile [d][kv]

    const int tid = threadIdx.x;
    const int w   = tid >> 6, lane = tid & 63;
    const int g   = lane >> 4, r16 = lane & 15;
    // bijective remap of the 1024 linear ids: each XCD gets 4 whole bh's
    const int m   = blockIdx.x + (blockIdx.y << 5) + (blockIdx.z << 9);
    const int bh  = (m & 7) + ((m >> 8) << 3);
    const int qb  = (m >> 3) & 31;
    const int q0  = qb * 64 + w * 16;
    const __bf16* Qp = Q + (size_t)bh * 2048 * 64;
    const __bf16* Kp = K + (size_t)bh * 2048 * 64;
    const __bf16* Vp = V + (size_t)bh * 64 * 2048;

    const int srow  = lane >> 3;
    const int scolV = 8 * ((lane & 7) ^ srow);                             // s = row&7
    const int scolK = 8 * ((lane & 7) ^ ((srow & 3) | ((w & 1) << 2)));    // s = (row&3)|((row>>3&1)<<2)
    const int swzK  = ((r16 & 3) | (((r16 >> 2) & 1) << 2)) << 4;
    const int swzV  = (r16 & 7) << 4;

    // Q fragments (B-operand): lane r16 = q, k = d
    bf16x8 qa[2];
#pragma unroll
    for (int kk = 0; kk < 2; ++kk)
        qa[kk] = *(const bf16x8*)(Qp + (size_t)(q0 + r16) * 64 + kk * 32 + g * 8);

    bf16x8 ones;
#pragma unroll
    for (int i = 0; i < 8; ++i) ones[i] = (__bf16)1.0f;

    f32x4 o[4] = {};
    f32x4 lsum = {};
    float mrun = 0.f;

    // per-thread staging source pointers (strength-reduced in the t loop)
    const int row0 = w * 8 + srow;           // r = 0 row
    const int row1 = 32 + w * 8 + srow;      // r = 1 row
    const char* kp0 = (const char*)(Kp + (size_t)row0 * 64 + scolK);
    const char* kp1 = (const char*)(Kp + (size_t)row1 * 64 + scolK);
    const char* vp0 = (const char*)(Vp + (size_t)row0 * 2048 + scolV);
    const char* vp1 = (const char*)(Vp + (size_t)row1 * 2048 + scolV);
    const int ldsb0 = w * 1024, ldsb1 = 4096 + w * 1024;

    // ---- stage tile 0 ----
    __builtin_amdgcn_global_load_lds(AS1(kp0), AS3((char*)&sK[0][0] + ldsb0), 16, 0, 0);
    __builtin_amdgcn_global_load_lds(AS1(kp1), AS3((char*)&sK[0][0] + ldsb1), 16, 0, 0);
    __builtin_amdgcn_global_load_lds(AS1(vp0), AS3((char*)&sV[0][0] + ldsb0), 16, 0, 0);
    __builtin_amdgcn_global_load_lds(AS1(vp1), AS3((char*)&sV[0][0] + ldsb1), 16, 0, 0);
    kp0 += 8192; kp1 += 8192; vp0 += 128; vp1 += 128;
    __syncthreads();

    for (int t = 0; t < 32; ++t) {
        const int cur = t & 1;
        if (t < 31) {
            char* const kd = (char*)&sK[cur ^ 1][0];
            char* const vd = (char*)&sV[cur ^ 1][0];
            __builtin_amdgcn_global_load_lds(AS1(kp0), AS3(kd + ldsb0), 16, 0, 0);
            __builtin_amdgcn_global_load_lds(AS1(kp1), AS3(kd + ldsb1), 16, 0, 0);
            __builtin_amdgcn_global_load_lds(AS1(vp0), AS3(vd + ldsb0), 16, 0, 0);
            __builtin_amdgcn_global_load_lds(AS1(vp1), AS3(vd + ldsb1), 16, 0, 0);
            kp0 += 8192; kp1 += 8192; vp0 += 128; vp1 += 128;
        }
        // ---- S' = K Q^T - mrun (C-init), sigma-permuted K rows ----
        bf16x8 kb[4][2];
#pragma unroll
        for (int nf = 0; nf < 4; ++nf) {
            const int row = ((nf >> 1) << 5) + ((r16 >> 2) << 3) + ((nf & 1) << 2) + (r16 & 3);
#pragma unroll
            for (int kk = 0; kk < 2; ++kk)
                kb[nf][kk] = *(const bf16x8*)((const char*)&sK[cur][0] + row * 128
                                              + ((kk * 64 + g * 16) ^ swzK));
        }
        const f32x4 cinit = { -mrun, -mrun, -mrun, -mrun };
        f32x4 S[4];
        __builtin_amdgcn_s_setprio(1);
#pragma unroll
        for (int nf = 0; nf < 4; ++nf) {
            f32x4 s = __builtin_amdgcn_mfma_f32_16x16x32_bf16(kb[nf][0], qa[0], cinit, 0, 0, 0);
            S[nf]   = __builtin_amdgcn_mfma_f32_16x16x32_bf16(kb[nf][1], qa[1], s, 0, 0, 0);
        }
        __builtin_amdgcn_s_setprio(0);
        // ---- defer-max: shfl-free common path ----
        float rm = fmaxf(fmaxf(S[0][0], S[0][1]), fmaxf(S[0][2], S[0][3]));
#pragma unroll
        for (int nf = 1; nf < 4; ++nf)
            rm = fmaxf(rm, fmaxf(fmaxf(S[nf][0], S[nf][1]), fmaxf(S[nf][2], S[nf][3])));
        if (!__all(rm <= 8.f)) {
            rm = fmaxf(rm, __shfl_xor(rm, 16));
            rm = fmaxf(rm, __shfl_xor(rm, 32));
            const float delta = fmaxf(rm, 0.f);
            const float al = __builtin_amdgcn_exp2f(-delta);
#pragma unroll
            for (int df = 0; df < 4; ++df)
#pragma unroll
                for (int reg = 0; reg < 4; ++reg) o[df][reg] *= al;
#pragma unroll
            for (int reg = 0; reg < 4; ++reg) lsum[reg] *= al;
            mrun += delta;
#pragma unroll
            for (int nf = 0; nf < 4; ++nf)
#pragma unroll
                for (int reg = 0; reg < 4; ++reg) S[nf][reg] -= delta;
        }
        // ---- P = exp2(S'), packed straight into PV B-fragments ----
        bf16x8 pb[2];
#pragma unroll
        for (int kk = 0; kk < 2; ++kk) {
            bf16x8 tpk;
            tpk[0] = (__bf16)__builtin_amdgcn_exp2f(S[kk * 2][0]);
            tpk[1] = (__bf16)__builtin_amdgcn_exp2f(S[kk * 2][1]);
            tpk[2] = (__bf16)__builtin_amdgcn_exp2f(S[kk * 2][2]);
            tpk[3] = (__bf16)__builtin_amdgcn_exp2f(S[kk * 2][3]);
            tpk[4] = (__bf16)__builtin_amdgcn_exp2f(S[kk * 2 + 1][0]);
            tpk[5] = (__bf16)__builtin_amdgcn_exp2f(S[kk * 2 + 1][1]);
            tpk[6] = (__bf16)__builtin_amdgcn_exp2f(S[kk * 2 + 1][2]);
            tpk[7] = (__bf16)__builtin_amdgcn_exp2f(S[kk * 2 + 1][3]);
            pb[kk] = tpk;
        }
        // ---- O_T += V_T P_T ; denominator via ones-MFMA ----
        __builtin_amdgcn_s_setprio(1);
        lsum = __builtin_amdgcn_mfma_f32_16x16x32_bf16(ones, pb[0], lsum, 0, 0, 0);
        lsum = __builtin_amdgcn_mfma_f32_16x16x32_bf16(ones, pb[1], lsum, 0, 0, 0);
#pragma unroll
        for (int kk = 0; kk < 2; ++kk)
#pragma unroll
            for (int df = 0; df < 4; ++df) {
                const int row = df * 16 + r16;
                bf16x8 vb = *(const bf16x8*)((const char*)&sV[cur][0] + row * 128
                                             + ((kk * 64 + g * 16) ^ swzV));
                o[df] = __builtin_amdgcn_mfma_f32_16x16x32_bf16(vb, pb[kk], o[df], 0, 0, 0);
            }
        __builtin_amdgcn_s_setprio(0);
        __syncthreads();
    }

    // ---- store O_T -> Os[token][c] (lsum already the full denominator) ----
    const float inv = 1.f / lsum[0];
    const size_t token = (size_t)(bh >> 4) * 2048 + q0 + r16;
#pragma unroll
    for (int df = 0; df < 4; ++df) {
        bf16x4 ov = { (__bf16)(o[df][0] * inv), (__bf16)(o[df][1] * inv),
                      (__bf16)(o[df][2] * inv), (__bf16)(o[df][3] * inv) };
        *(bf16x4*)(O + token * 1024 + (bh & 15) * 64 + df * 16 + g * 4) = ov;
    }
}

// ---------------------------------------------------------------------------
extern "C" void kernel_launch(void* const* d_in, const int* in_sizes, int n_in,
                              void* d_out, int out_size, void* d_ws, size_t ws_size,
                              hipStream_t stream)
{
    const float* x     = (const float*)d_in[0];
    const float* Wqkv  = (const float*)d_in[1];
    const float* bqkv  = (const float*)d_in[2];
    const float* Wproj = (const float*)d_in[3];
    const float* bproj = (const float*)d_in[4];
    float* out = (float*)d_out;

    const size_t NX   = (size_t)4096 * 1024;
    const size_t NWQ  = (size_t)3072 * 1024;
    const size_t NWP  = (size_t)1024 * 1024;

    __bf16* xb  = (__bf16*)d_ws;
    __bf16* Wqb = xb  + NX;
    __bf16* Wpb = Wqb + NWQ;
    __bf16* Qs  = Wpb + NWP;           // (B,H,T,64), scaled 0.125*log2e
    __bf16* Ks  = Qs  + NX;            // (B,H,T,64)
    __bf16* Vt  = Ks  + NX;            // (B,H,64,T)
    __bf16* Os  = Vt  + NX;            // (B*T, C)

    cvt_all<<<dim3(2048), dim3(256), 0, stream>>>(x, Wqkv, Wproj, xb, Wqb, Wpb,
                                                  (int)NX, (int)NWQ, (int)NWP);
    gemm_bt<0><<<dim3(24, 32), dim3(256), 0, stream>>>(xb, Wqb, bqkv, 4096, 3072, 1024, Qs, Ks, Vt, nullptr);
    attn<<<dim3(32, 16, 2), dim3(256), 0, stream>>>(Qs, Ks, Vt, Os);
    gemm_bt<1><<<dim3(8, 32), dim3(256), 0, stream>>>(Os, Wpb, bproj, 4096, 1024, 1024, nullptr, nullptr, nullptr, out);
}

// Round 12
// 119.480 us; speedup vs baseline: 1.2300x; 1.0197x over previous
//
#include <hip/hip_runtime.h>

// MHSA: B=2, T=2048, C=1024, H=16, hd=64. Inputs f32, output f32.
// cvt(all->bf16) -> QKV GEMM (XCD-swizzled; scatter Q*0.125*log2e, K, V^T,
// packed V stores) -> flash attn (swapped QK^T; sigma-permuted K rows => P in
// registers; 32q/wave, 2-wave blocks, 5 blocks/CU; C-init=-mrun; ones-MFMA
// denominator; raw v_exp_f32; bh-grouped XCD remap) -> proj GEMM (f32 out).

typedef __bf16 bf16x4 __attribute__((ext_vector_type(4)));
typedef __bf16 bf16x8 __attribute__((ext_vector_type(8)));
typedef float  f32x4  __attribute__((ext_vector_type(4)));

#define AS1(p) ((const __attribute__((address_space(1))) void*)(p))
#define AS3(p) ((__attribute__((address_space(3))) void*)(p))

// ---------------------------------------------------------------------------
__global__ __launch_bounds__(256)
void cvt_all(const float* __restrict__ a, const float* __restrict__ b,
             const float* __restrict__ c, __bf16* __restrict__ oa,
             __bf16* __restrict__ ob, __bf16* __restrict__ oc,
             int na, int nb, int nc)
{
    const int total = (na + nb + nc) >> 2;
    const int stride = gridDim.x * blockDim.x;
    for (int i4 = blockIdx.x * blockDim.x + threadIdx.x; i4 < total; i4 += stride) {
        int i = i4 << 2;
        const float* src; __bf16* dst;
        if (i < na)               { src = a + i;             dst = oa + i; }
        else if (i < na + nb)     { src = b + (i - na);      dst = ob + (i - na); }
        else                      { src = c + (i - na - nb); dst = oc + (i - na - nb); }
        const float4 v = *(const float4*)src;
        bf16x4 o = { (__bf16)v.x, (__bf16)v.y, (__bf16)v.z, (__bf16)v.w };
        *(bf16x4*)dst = o;
    }
}

// ---------------------------------------------------------------------------
// GEMM out[m][n] = sum_k A[m][k]*W[n][k] + bias[n]. 128x128 tile, BK=64.
// XCD-bijective block swizzle. MODE 0: QKV scatter epilogue (packed V^T
// stores). MODE 1: f32 out.
// ---------------------------------------------------------------------------
template<int MODE>
__global__ __launch_bounds__(256)
void gemm_bt(const __bf16* __restrict__ A, const __bf16* __restrict__ W,
             const float* __restrict__ bias, int M, int N, int K,
             __bf16* __restrict__ O0, __bf16* __restrict__ O1,
             __bf16* __restrict__ O2, float* __restrict__ Of)
{
    __shared__ __bf16 sA[128 * 64];
    __shared__ __bf16 sB[128 * 64];
    const int tid  = threadIdx.x;
    const int w    = tid >> 6, lane = tid & 63;
    const int g    = lane >> 4, r16 = lane & 15;
    const int lin  = blockIdx.y * gridDim.x + blockIdx.x;
    const int per  = (gridDim.x * gridDim.y) >> 3;
    const int nlin = (lin & 7) * per + (lin >> 3);
    const int tM   = (nlin / gridDim.x) * 128, tN = (nlin % gridDim.x) * 128;
    const int wr   = w >> 1, wc = w & 1;
    const int crow = lane >> 3;
    const int ccol = (lane & 7) * 8;

    f32x4 acc[4][4] = {};

    for (int k0 = 0; k0 < K; k0 += 64) {
#pragma unroll
        for (int c = w; c < 16; c += 4) {
            const __bf16* ga = A + (size_t)(tM + c * 8 + crow) * K + k0 + ccol;
            __builtin_amdgcn_global_load_lds(AS1(ga), AS3(&sA[c * 8 * 64]), 16, 0, 0);
            const __bf16* gb = W + (size_t)(tN + c * 8 + crow) * K + k0 + ccol;
            __builtin_amdgcn_global_load_lds(AS1(gb), AS3(&sB[c * 8 * 64]), 16, 0, 0);
        }
        __syncthreads();
#pragma unroll
        for (int kk = 0; kk < 2; ++kk) {
            bf16x8 a[4], b[4];
#pragma unroll
            for (int mf = 0; mf < 4; ++mf)
                a[mf] = *(const bf16x8*)&sA[(wr * 64 + mf * 16 + r16) * 64 + kk * 32 + g * 8];
#pragma unroll
            for (int nf = 0; nf < 4; ++nf)
                b[nf] = *(const bf16x8*)&sB[(wc * 64 + nf * 16 + r16) * 64 + kk * 32 + g * 8];
#pragma unroll
            for (int mf = 0; mf < 4; ++mf)
#pragma unroll
                for (int nf = 0; nf < 4; ++nf)
                    acc[mf][nf] = __builtin_amdgcn_mfma_f32_16x16x32_bf16(
                        a[mf], b[nf], acc[mf][nf], 0, 0, 0);
        }
        __syncthreads();
    }

#pragma unroll
    for (int mf = 0; mf < 4; ++mf) {
#pragma unroll
        for (int nf = 0; nf < 4; ++nf) {
            if (MODE == 0) {
                const int col  = tN + wc * 64 + nf * 16 + r16;
                const int h    = col / 192, j = col % 192;
                const int rowb = tM + wr * 64 + mf * 16 + g * 4;
                const int b    = rowb >> 11, t = rowb & 2047;
                const size_t bh = (size_t)(b * 16 + h);
                const float bs = bias[col];
                if (j >= 128) {
                    bf16x4 pk = { (__bf16)(acc[mf][nf][0] + bs), (__bf16)(acc[mf][nf][1] + bs),
                                  (__bf16)(acc[mf][nf][2] + bs), (__bf16)(acc[mf][nf][3] + bs) };
                    *(bf16x4*)&O2[(bh * 64 + (j - 128)) * 2048 + t] = pk;
                } else if (j < 64) {
#pragma unroll
                    for (int reg = 0; reg < 4; ++reg)
                        O0[(bh * 2048 + t + reg) * 64 + j] =
                            (__bf16)((acc[mf][nf][reg] + bs) * 0.18033688011112042f);
                } else {
#pragma unroll
                    for (int reg = 0; reg < 4; ++reg)
                        O1[(bh * 2048 + t + reg) * 64 + (j - 64)] =
                            (__bf16)(acc[mf][nf][reg] + bs);
                }
            } else {
#pragma unroll
                for (int reg = 0; reg < 4; ++reg) {
                    const int row = tM + wr * 64 + mf * 16 + g * 4 + reg;
                    const int col = tN + wc * 64 + nf * 16 + r16;
                    Of[(size_t)row * N + col] = acc[mf][nf][reg] + bias[col];
                }
            }
        }
    }
}

// ---------------------------------------------------------------------------
// Flash attention, swapped QK^T, 32 q/wave, 2-wave blocks (64 q), grid 1024,
// 5 blocks/CU (LDS 32KB), bh-grouped XCD remap. Shared kb/vb LDS reads feed
// both q sub-blocks (h=0,1): LDS-read bytes per q halved vs 16q/wave.
// Sigma-permuted K rows keep P in registers; C-init=-mrun; ones-MFMA lsum;
// raw v_exp_f32; shfl-free defer-max.
// ---------------------------------------------------------------------------
__global__ __launch_bounds__(128, 2)
void attn(const __bf16* __restrict__ Q, const __bf16* __restrict__ K,
          const __bf16* __restrict__ V, __bf16* __restrict__ O)
{
    __shared__ __bf16 sK[2][64 * 64];   // 8 KB each
    __shared__ __bf16 sV[2][64 * 64];   // V^T tile [d][kv]

    const int tid = threadIdx.x;
    const int w   = tid >> 6, lane = tid & 63;
    const int g   = lane >> 4, r16 = lane & 15;
    // bijective remap of the 1024 linear ids: each XCD gets 4 whole bh's
    const int m   = blockIdx.x + (blockIdx.y << 5) + (blockIdx.z << 9);
    const int bh  = (m & 7) + ((m >> 8) << 3);
    const int qb  = (m >> 3) & 31;
    const int q0  = qb * 64 + w * 32;                  // wave's 32 q-rows
    const __bf16* Qp = Q + (size_t)bh * 2048 * 64;
    const __bf16* Kp = K + (size_t)bh * 2048 * 64;
    const __bf16* Vp = V + (size_t)bh * 64 * 2048;

    const int srow  = lane >> 3;
    const int scolV = 8 * ((lane & 7) ^ srow);         // s = row&7 (row%8 == srow)
    // K involution s(row) = (row&3)|(((row>>3)&1)<<2); (row>>3)&1 == r&1 here
    const int scolK0 = 8 * ((lane & 7) ^ (srow & 3));            // r even
    const int scolK1 = 8 * ((lane & 7) ^ ((srow & 3) | 4));      // r odd
    const int swzK  = ((r16 & 3) | (((r16 >> 2) & 1) << 2)) << 4;
    const int swzV  = (r16 & 7) << 4;

    // Q fragments (B-operand): lane r16 = q, k = d; h = q sub-block
    bf16x8 qa[2][2];
#pragma unroll
    for (int h = 0; h < 2; ++h)
#pragma unroll
        for (int kk = 0; kk < 2; ++kk)
            qa[h][kk] = *(const bf16x8*)(Qp + (size_t)(q0 + h * 16 + r16) * 64 + kk * 32 + g * 8);

    bf16x8 ones;
#pragma unroll
    for (int i = 0; i < 8; ++i) ones[i] = (__bf16)1.0f;

    f32x4 o[2][4] = {};
    f32x4 lsum[2] = {};
    float mrun[2] = { 0.f, 0.f };

    // per-thread staging pointers: wave w stages rows [w*32, w*32+32)
    const char* kp[4]; const char* vp[4]; int ldsb[4];
#pragma unroll
    for (int r = 0; r < 4; ++r) {
        const int row = w * 32 + r * 8 + srow;
        kp[r]   = (const char*)(Kp + (size_t)row * 64 + ((r & 1) ? scolK1 : scolK0));
        vp[r]   = (const char*)(Vp + (size_t)row * 2048 + scolV);
        ldsb[r] = w * 4096 + r * 1024;
    }

    // ---- stage tile 0 ----
#pragma unroll
    for (int r = 0; r < 4; ++r) {
        __builtin_amdgcn_global_load_lds(AS1(kp[r]), AS3((char*)&sK[0][0] + ldsb[r]), 16, 0, 0);
        __builtin_amdgcn_global_load_lds(AS1(vp[r]), AS3((char*)&sV[0][0] + ldsb[r]), 16, 0, 0);
        kp[r] += 8192; vp[r] += 128;
    }
    __syncthreads();

    for (int t = 0; t < 32; ++t) {
        const int cur = t & 1;
        if (t < 31) {
            char* const kd = (char*)&sK[cur ^ 1][0];
            char* const vd = (char*)&sV[cur ^ 1][0];
#pragma unroll
            for (int r = 0; r < 4; ++r) {
                __builtin_amdgcn_global_load_lds(AS1(kp[r]), AS3(kd + ldsb[r]), 16, 0, 0);
                __builtin_amdgcn_global_load_lds(AS1(vp[r]), AS3(vd + ldsb[r]), 16, 0, 0);
                kp[r] += 8192; vp[r] += 128;
            }
        }
        // ---- S'[h] = K Q^T - mrun[h] (C-init), sigma-permuted K rows ----
        bf16x8 kb[4][2];
#pragma unroll
        for (int nf = 0; nf < 4; ++nf) {
            const int row = ((nf >> 1) << 5) + ((r16 >> 2) << 3) + ((nf & 1) << 2) + (r16 & 3);
#pragma unroll
            for (int kk = 0; kk < 2; ++kk)
                kb[nf][kk] = *(const bf16x8*)((const char*)&sK[cur][0] + row * 128
                                              + ((kk * 64 + g * 16) ^ swzK));
        }
        f32x4 S[2][4];
        __builtin_amdgcn_s_setprio(1);
#pragma unroll
        for (int h = 0; h < 2; ++h) {
            const f32x4 cinit = { -mrun[h], -mrun[h], -mrun[h], -mrun[h] };
#pragma unroll
            for (int nf = 0; nf < 4; ++nf) {
                f32x4 s = __builtin_amdgcn_mfma_f32_16x16x32_bf16(kb[nf][0], qa[h][0], cinit, 0, 0, 0);
                S[h][nf] = __builtin_amdgcn_mfma_f32_16x16x32_bf16(kb[nf][1], qa[h][1], s, 0, 0, 0);
            }
        }
        __builtin_amdgcn_s_setprio(0);
        // ---- defer-max: shfl-free common path ----
        float rm[2];
#pragma unroll
        for (int h = 0; h < 2; ++h) {
            float m0 = fmaxf(fmaxf(S[h][0][0], S[h][0][1]), fmaxf(S[h][0][2], S[h][0][3]));
#pragma unroll
            for (int nf = 1; nf < 4; ++nf)
                m0 = fmaxf(m0, fmaxf(fmaxf(S[h][nf][0], S[h][nf][1]),
                                     fmaxf(S[h][nf][2], S[h][nf][3])));
            rm[h] = m0;
        }
        if (!__all(rm[0] <= 8.f && rm[1] <= 8.f)) {
#pragma unroll
            for (int h = 0; h < 2; ++h) {
                float r0 = rm[h];
                r0 = fmaxf(r0, __shfl_xor(r0, 16));
                r0 = fmaxf(r0, __shfl_xor(r0, 32));
                const float delta = fmaxf(r0, 0.f);
                const float al = __builtin_amdgcn_exp2f(-delta);
#pragma unroll
                for (int df = 0; df < 4; ++df)
#pragma unroll
                    for (int reg = 0; reg < 4; ++reg) o[h][df][reg] *= al;
#pragma unroll
                for (int reg = 0; reg < 4; ++reg) lsum[h][reg] *= al;
                mrun[h] += delta;
#pragma unroll
                for (int nf = 0; nf < 4; ++nf)
#pragma unroll
                    for (int reg = 0; reg < 4; ++reg) S[h][nf][reg] -= delta;
            }
        }
        // ---- P = exp2(S'), packed straight into PV B-fragments ----
        bf16x8 pb[2][2];
#pragma unroll
        for (int h = 0; h < 2; ++h)
#pragma unroll
            for (int kk = 0; kk < 2; ++kk) {
                bf16x8 tpk;
                tpk[0] = (__bf16)__builtin_amdgcn_exp2f(S[h][kk * 2][0]);
                tpk[1] = (__bf16)__builtin_amdgcn_exp2f(S[h][kk * 2][1]);
                tpk[2] = (__bf16)__builtin_amdgcn_exp2f(S[h][kk * 2][2]);
                tpk[3] = (__bf16)__builtin_amdgcn_exp2f(S[h][kk * 2][3]);
                tpk[4] = (__bf16)__builtin_amdgcn_exp2f(S[h][kk * 2 + 1][0]);
                tpk[5] = (__bf16)__builtin_amdgcn_exp2f(S[h][kk * 2 + 1][1]);
                tpk[6] = (__bf16)__builtin_amdgcn_exp2f(S[h][kk * 2 + 1][2]);
                tpk[7] = (__bf16)__builtin_amdgcn_exp2f(S[h][kk * 2 + 1][3]);
                pb[h][kk] = tpk;
            }
        // ---- O_T += V_T P_T ; denominator via ones-MFMA (vb shared by h) ----
        __builtin_amdgcn_s_setprio(1);
#pragma unroll
        for (int h = 0; h < 2; ++h) {
            lsum[h] = __builtin_amdgcn_mfma_f32_16x16x32_bf16(ones, pb[h][0], lsum[h], 0, 0, 0);
            lsum[h] = __builtin_amdgcn_mfma_f32_16x16x32_bf16(ones, pb[h][1], lsum[h], 0, 0, 0);
        }
#pragma unroll
        for (int kk = 0; kk < 2; ++kk)
#pragma unroll
            for (int df = 0; df < 4; ++df) {
                const int row = df * 16 + r16;
                bf16x8 vb = *(const bf16x8*)((const char*)&sV[cur][0] + row * 128
                                             + ((kk * 64 + g * 16) ^ swzV));
#pragma unroll
                for (int h = 0; h < 2; ++h)
                    o[h][df] = __builtin_amdgcn_mfma_f32_16x16x32_bf16(vb, pb[h][kk], o[h][df], 0, 0, 0);
            }
        __builtin_amdgcn_s_setprio(0);
        __syncthreads();
    }

    // ---- store O_T -> Os[token][c] ----
#pragma unroll
    for (int h = 0; h < 2; ++h) {
        const float inv = 1.f / lsum[h][0];
        const size_t token = (size_t)(bh >> 4) * 2048 + q0 + h * 16 + r16;
#pragma unroll
        for (int df = 0; df < 4; ++df) {
            bf16x4 ov = { (__bf16)(o[h][df][0] * inv), (__bf16)(o[h][df][1] * inv),
                          (__bf16)(o[h][df][2] * inv), (__bf16)(o[h][df][3] * inv) };
            *(bf16x4*)(O + token * 1024 + (bh & 15) * 64 + df * 16 + g * 4) = ov;
        }
    }
}

// ---------------------------------------------------------------------------
extern "C" void kernel_launch(void* const* d_in, const int* in_sizes, int n_in,
                              void* d_out, int out_size, void* d_ws, size_t ws_size,
                              hipStream_t stream)
{
    const float* x     = (const float*)d_in[0];
    const float* Wqkv  = (const float*)d_in[1];
    const float* bqkv  = (const float*)d_in[2];
    const float* Wproj = (const float*)d_in[3];
    const float* bproj = (const float*)d_in[4];
    float* out = (float*)d_out;

    const size_t NX   = (size_t)4096 * 1024;
    const size_t NWQ  = (size_t)3072 * 1024;
    const size_t NWP  = (size_t)1024 * 1024;

    __bf16* xb  = (__bf16*)d_ws;
    __bf16* Wqb = xb  + NX;
    __bf16* Wpb = Wqb + NWQ;
    __bf16* Qs  = Wpb + NWP;           // (B,H,T,64), scaled 0.125*log2e
    __bf16* Ks  = Qs  + NX;            // (B,H,T,64)
    __bf16* Vt  = Ks  + NX;            // (B,H,64,T)
    __bf16* Os  = Vt  + NX;            // (B*T, C)

    cvt_all<<<dim3(2048), dim3(256), 0, stream>>>(x, Wqkv, Wproj, xb, Wqb, Wpb,
                                                  (int)NX, (int)NWQ, (int)NWP);
    gemm_bt<0><<<dim3(24, 32), dim3(256), 0, stream>>>(xb, Wqb, bqkv, 4096, 3072, 1024, Qs, Ks, Vt, nullptr);
    attn<<<dim3(32, 16, 2), dim3(128), 0, stream>>>(Qs, Ks, Vt, Os);
    gemm_bt<1><<<dim3(8, 32), dim3(256), 0, stream>>>(Os, Wpb, bproj, 4096, 1024, 1024, nullptr, nullptr, nullptr, out);
}

// Round 13
// 119.409 us; speedup vs baseline: 1.2307x; 1.0006x over previous
//
#include <hip/hip_runtime.h>

// MHSA: B=2, T=2048, C=1024, H=16, hd=64. Inputs f32, output f32.
// cvt(all->bf16) -> QKV GEMM (XCD-swizzled; scatter Q*0.125*log2e, K, V^T,
// packed V stores) -> flash attn (r11 config: swapped QK^T; sigma-permuted K
// rows => P in registers; 16q/wave, 4-wave blocks, grid 1024; C-init=-mrun;
// ones-MFMA denominator; raw v_exp_f32; bh-grouped XCD remap) -> proj GEMM
// (128x64 tile, 512 blocks for 2x occupancy, f32 out).

typedef __bf16 bf16x4 __attribute__((ext_vector_type(4)));
typedef __bf16 bf16x8 __attribute__((ext_vector_type(8)));
typedef float  f32x4  __attribute__((ext_vector_type(4)));

#define AS1(p) ((const __attribute__((address_space(1))) void*)(p))
#define AS3(p) ((__attribute__((address_space(3))) void*)(p))

// ---------------------------------------------------------------------------
__global__ __launch_bounds__(256)
void cvt_all(const float* __restrict__ a, const float* __restrict__ b,
             const float* __restrict__ c, __bf16* __restrict__ oa,
             __bf16* __restrict__ ob, __bf16* __restrict__ oc,
             int na, int nb, int nc)
{
    const int total = (na + nb + nc) >> 2;
    const int stride = gridDim.x * blockDim.x;
    for (int i4 = blockIdx.x * blockDim.x + threadIdx.x; i4 < total; i4 += stride) {
        int i = i4 << 2;
        const float* src; __bf16* dst;
        if (i < na)               { src = a + i;             dst = oa + i; }
        else if (i < na + nb)     { src = b + (i - na);      dst = ob + (i - na); }
        else                      { src = c + (i - na - nb); dst = oc + (i - na - nb); }
        const float4 v = *(const float4*)src;
        bf16x4 o = { (__bf16)v.x, (__bf16)v.y, (__bf16)v.z, (__bf16)v.w };
        *(bf16x4*)dst = o;
    }
}

// ---------------------------------------------------------------------------
// QKV GEMM out[m][n] = sum_k A[m][k]*W[n][k] + bias[n]. 128x128 tile, BK=64.
// XCD-bijective block swizzle. Scatter epilogue (packed V^T stores).
// ---------------------------------------------------------------------------
__global__ __launch_bounds__(256)
void gemm_qkv(const __bf16* __restrict__ A, const __bf16* __restrict__ W,
              const float* __restrict__ bias, int K,
              __bf16* __restrict__ O0, __bf16* __restrict__ O1,
              __bf16* __restrict__ O2)
{
    __shared__ __bf16 sA[128 * 64];
    __shared__ __bf16 sB[128 * 64];
    const int tid  = threadIdx.x;
    const int w    = tid >> 6, lane = tid & 63;
    const int g    = lane >> 4, r16 = lane & 15;
    const int lin  = blockIdx.y * gridDim.x + blockIdx.x;
    const int per  = (gridDim.x * gridDim.y) >> 3;
    const int nlin = (lin & 7) * per + (lin >> 3);
    const int tM   = (nlin / gridDim.x) * 128, tN = (nlin % gridDim.x) * 128;
    const int wr   = w >> 1, wc = w & 1;
    const int crow = lane >> 3;
    const int ccol = (lane & 7) * 8;

    f32x4 acc[4][4] = {};

    for (int k0 = 0; k0 < K; k0 += 64) {
#pragma unroll
        for (int c = w; c < 16; c += 4) {
            const __bf16* ga = A + (size_t)(tM + c * 8 + crow) * K + k0 + ccol;
            __builtin_amdgcn_global_load_lds(AS1(ga), AS3(&sA[c * 8 * 64]), 16, 0, 0);
            const __bf16* gb = W + (size_t)(tN + c * 8 + crow) * K + k0 + ccol;
            __builtin_amdgcn_global_load_lds(AS1(gb), AS3(&sB[c * 8 * 64]), 16, 0, 0);
        }
        __syncthreads();
#pragma unroll
        for (int kk = 0; kk < 2; ++kk) {
            bf16x8 a[4], b[4];
#pragma unroll
            for (int mf = 0; mf < 4; ++mf)
                a[mf] = *(const bf16x8*)&sA[(wr * 64 + mf * 16 + r16) * 64 + kk * 32 + g * 8];
#pragma unroll
            for (int nf = 0; nf < 4; ++nf)
                b[nf] = *(const bf16x8*)&sB[(wc * 64 + nf * 16 + r16) * 64 + kk * 32 + g * 8];
#pragma unroll
            for (int mf = 0; mf < 4; ++mf)
#pragma unroll
                for (int nf = 0; nf < 4; ++nf)
                    acc[mf][nf] = __builtin_amdgcn_mfma_f32_16x16x32_bf16(
                        a[mf], b[nf], acc[mf][nf], 0, 0, 0);
        }
        __syncthreads();
    }

#pragma unroll
    for (int mf = 0; mf < 4; ++mf) {
#pragma unroll
        for (int nf = 0; nf < 4; ++nf) {
            const int col  = tN + wc * 64 + nf * 16 + r16;
            const int h    = col / 192, j = col % 192;
            const int rowb = tM + wr * 64 + mf * 16 + g * 4;
            const int b    = rowb >> 11, t = rowb & 2047;
            const size_t bh = (size_t)(b * 16 + h);
            const float bs = bias[col];
            if (j >= 128) {
                bf16x4 pk = { (__bf16)(acc[mf][nf][0] + bs), (__bf16)(acc[mf][nf][1] + bs),
                              (__bf16)(acc[mf][nf][2] + bs), (__bf16)(acc[mf][nf][3] + bs) };
                *(bf16x4*)&O2[(bh * 64 + (j - 128)) * 2048 + t] = pk;
            } else if (j < 64) {
#pragma unroll
                for (int reg = 0; reg < 4; ++reg)
                    O0[(bh * 2048 + t + reg) * 64 + j] =
                        (__bf16)((acc[mf][nf][reg] + bs) * 0.18033688011112042f);
            } else {
#pragma unroll
                for (int reg = 0; reg < 4; ++reg)
                    O1[(bh * 2048 + t + reg) * 64 + (j - 64)] =
                        (__bf16)(acc[mf][nf][reg] + bs);
            }
        }
    }
}

// ---------------------------------------------------------------------------
// Proj GEMM: 128M x 64N tile, BK=64, 256 thr (4 waves 2x2, 64x32 each).
// Grid (16,32) = 512 blocks = 2/CU (2x occupancy vs 128x128). f32 out.
// ---------------------------------------------------------------------------
__global__ __launch_bounds__(256)
void gemm_proj(const __bf16* __restrict__ A, const __bf16* __restrict__ W,
               const float* __restrict__ bias, int N, int K,
               float* __restrict__ Of)
{
    __shared__ __bf16 sA[128 * 64];   // 16 KB
    __shared__ __bf16 sB[64 * 64];    //  8 KB
    const int tid  = threadIdx.x;
    const int w    = tid >> 6, lane = tid & 63;
    const int g    = lane >> 4, r16 = lane & 15;
    const int lin  = blockIdx.y * gridDim.x + blockIdx.x;
    const int per  = (gridDim.x * gridDim.y) >> 3;
    const int nlin = (lin & 7) * per + (lin >> 3);
    const int tM   = (nlin / gridDim.x) * 128, tN = (nlin % gridDim.x) * 64;
    const int wr   = w >> 1, wc = w & 1;
    const int crow = lane >> 3;
    const int ccol = (lane & 7) * 8;

    f32x4 acc[4][2] = {};

    for (int k0 = 0; k0 < K; k0 += 64) {
#pragma unroll
        for (int c = w; c < 16; c += 4) {
            const __bf16* ga = A + (size_t)(tM + c * 8 + crow) * K + k0 + ccol;
            __builtin_amdgcn_global_load_lds(AS1(ga), AS3(&sA[c * 8 * 64]), 16, 0, 0);
        }
#pragma unroll
        for (int c = w; c < 8; c += 4) {
            const __bf16* gb = W + (size_t)(tN + c * 8 + crow) * K + k0 + ccol;
            __builtin_amdgcn_global_load_lds(AS1(gb), AS3(&sB[c * 8 * 64]), 16, 0, 0);
        }
        __syncthreads();
#pragma unroll
        for (int kk = 0; kk < 2; ++kk) {
            bf16x8 a[4], b[2];
#pragma unroll
            for (int mf = 0; mf < 4; ++mf)
                a[mf] = *(const bf16x8*)&sA[(wr * 64 + mf * 16 + r16) * 64 + kk * 32 + g * 8];
#pragma unroll
            for (int nf = 0; nf < 2; ++nf)
                b[nf] = *(const bf16x8*)&sB[(wc * 32 + nf * 16 + r16) * 64 + kk * 32 + g * 8];
#pragma unroll
            for (int mf = 0; mf < 4; ++mf)
#pragma unroll
                for (int nf = 0; nf < 2; ++nf)
                    acc[mf][nf] = __builtin_amdgcn_mfma_f32_16x16x32_bf16(
                        a[mf], b[nf], acc[mf][nf], 0, 0, 0);
        }
        __syncthreads();
    }

#pragma unroll
    for (int mf = 0; mf < 4; ++mf)
#pragma unroll
        for (int nf = 0; nf < 2; ++nf) {
            const int col = tN + wc * 32 + nf * 16 + r16;
            const float bs = bias[col];
#pragma unroll
            for (int reg = 0; reg < 4; ++reg) {
                const int row = tM + wr * 64 + mf * 16 + g * 4 + reg;
                Of[(size_t)row * N + col] = acc[mf][nf][reg] + bs;
            }
        }
}

// ---------------------------------------------------------------------------
// Flash attention (r11 champion config): swapped QK^T, 16 q/wave, 4-wave
// blocks, grid 1024, bh-grouped XCD remap. K/V^T staged in LDS (dbuf,
// swizzled); sigma-permuted K rows keep P in registers. C-init=-mrun,
// ones-MFMA denominator, raw v_exp_f32, strength-reduced staging pointers.
// ---------------------------------------------------------------------------
__global__ __launch_bounds__(256, 4)
void attn(const __bf16* __restrict__ Q, const __bf16* __restrict__ K,
          const __bf16* __restrict__ V, __bf16* __restrict__ O)
{
    __shared__ __bf16 sK[2][64 * 64];   // 8 KB each
    __shared__ __bf16 sV[2][64 * 64];   // V^T tile [d][kv]

    const int tid = threadIdx.x;
    const int w   = tid >> 6, lane = tid & 63;
    const int g   = lane >> 4, r16 = lane & 15;
    const int m   = blockIdx.x + (blockIdx.y << 5) + (blockIdx.z << 9);
    const int bh  = (m & 7) + ((m >> 8) << 3);
    const int qb  = (m >> 3) & 31;
    const int q0  = qb * 64 + w * 16;
    const __bf16* Qp = Q + (size_t)bh * 2048 * 64;
    const __bf16* Kp = K + (size_t)bh * 2048 * 64;
    const __bf16* Vp = V + (size_t)bh * 64 * 2048;

    const int srow  = lane >> 3;
    const int scolV = 8 * ((lane & 7) ^ srow);
    const int scolK = 8 * ((lane & 7) ^ ((srow & 3) | ((w & 1) << 2)));
    const int swzK  = ((r16 & 3) | (((r16 >> 2) & 1) << 2)) << 4;
    const int swzV  = (r16 & 7) << 4;

    bf16x8 qa[2];
#pragma unroll
    for (int kk = 0; kk < 2; ++kk)
        qa[kk] = *(const bf16x8*)(Qp + (size_t)(q0 + r16) * 64 + kk * 32 + g * 8);

    bf16x8 ones;
#pragma unroll
    for (int i = 0; i < 8; ++i) ones[i] = (__bf16)1.0f;

    f32x4 o[4] = {};
    f32x4 lsum = {};
    float mrun = 0.f;

    const int row0 = w * 8 + srow;
    const int row1 = 32 + w * 8 + srow;
    const char* kp0 = (const char*)(Kp + (size_t)row0 * 64 + scolK);
    const char* kp1 = (const char*)(Kp + (size_t)row1 * 64 + scolK);
    const char* vp0 = (const char*)(Vp + (size_t)row0 * 2048 + scolV);
    const char* vp1 = (const char*)(Vp + (size_t)row1 * 2048 + scolV);
    const int ldsb0 = w * 1024, ldsb1 = 4096 + w * 1024;

    __builtin_amdgcn_global_load_lds(AS1(kp0), AS3((char*)&sK[0][0] + ldsb0), 16, 0, 0);
    __builtin_amdgcn_global_load_lds(AS1(kp1), AS3((char*)&sK[0][0] + ldsb1), 16, 0, 0);
    __builtin_amdgcn_global_load_lds(AS1(vp0), AS3((char*)&sV[0][0] + ldsb0), 16, 0, 0);
    __builtin_amdgcn_global_load_lds(AS1(vp1), AS3((char*)&sV[0][0] + ldsb1), 16, 0, 0);
    kp0 += 8192; kp1 += 8192; vp0 += 128; vp1 += 128;
    __syncthreads();

    for (int t = 0; t < 32; ++t) {
        const int cur = t & 1;
        if (t < 31) {
            char* const kd = (char*)&sK[cur ^ 1][0];
            char* const vd = (char*)&sV[cur ^ 1][0];
            __builtin_amdgcn_global_load_lds(AS1(kp0), AS3(kd + ldsb0), 16, 0, 0);
            __builtin_amdgcn_global_load_lds(AS1(kp1), AS3(kd + ldsb1), 16, 0, 0);
            __builtin_amdgcn_global_load_lds(AS1(vp0), AS3(vd + ldsb0), 16, 0, 0);
            __builtin_amdgcn_global_load_lds(AS1(vp1), AS3(vd + ldsb1), 16, 0, 0);
            kp0 += 8192; kp1 += 8192; vp0 += 128; vp1 += 128;
        }
        bf16x8 kb[4][2];
#pragma unroll
        for (int nf = 0; nf < 4; ++nf) {
            const int row = ((nf >> 1) << 5) + ((r16 >> 2) << 3) + ((nf & 1) << 2) + (r16 & 3);
#pragma unroll
            for (int kk = 0; kk < 2; ++kk)
                kb[nf][kk] = *(const bf16x8*)((const char*)&sK[cur][0] + row * 128
                                              + ((kk * 64 + g * 16) ^ swzK));
        }
        const f32x4 cinit = { -mrun, -mrun, -mrun, -mrun };
        f32x4 S[4];
        __builtin_amdgcn_s_setprio(1);
#pragma unroll
        for (int nf = 0; nf < 4; ++nf) {
            f32x4 s = __builtin_amdgcn_mfma_f32_16x16x32_bf16(kb[nf][0], qa[0], cinit, 0, 0, 0);
            S[nf]   = __builtin_amdgcn_mfma_f32_16x16x32_bf16(kb[nf][1], qa[1], s, 0, 0, 0);
        }
        __builtin_amdgcn_s_setprio(0);
        float rm = fmaxf(fmaxf(S[0][0], S[0][1]), fmaxf(S[0][2], S[0][3]));
#pragma unroll
        for (int nf = 1; nf < 4; ++nf)
            rm = fmaxf(rm, fmaxf(fmaxf(S[nf][0], S[nf][1]), fmaxf(S[nf][2], S[nf][3])));
        if (!__all(rm <= 8.f)) {
            rm = fmaxf(rm, __shfl_xor(rm, 16));
            rm = fmaxf(rm, __shfl_xor(rm, 32));
            const float delta = fmaxf(rm, 0.f);
            const float al = __builtin_amdgcn_exp2f(-delta);
#pragma unroll
            for (int df = 0; df < 4; ++df)
#pragma unroll
                for (int reg = 0; reg < 4; ++reg) o[df][reg] *= al;
#pragma unroll
            for (int reg = 0; reg < 4; ++reg) lsum[reg] *= al;
            mrun += delta;
#pragma unroll
            for (int nf = 0; nf < 4; ++nf)
#pragma unroll
                for (int reg = 0; reg < 4; ++reg) S[nf][reg] -= delta;
        }
        bf16x8 pb[2];
#pragma unroll
        for (int kk = 0; kk < 2; ++kk) {
            bf16x8 tpk;
            tpk[0] = (__bf16)__builtin_amdgcn_exp2f(S[kk * 2][0]);
            tpk[1] = (__bf16)__builtin_amdgcn_exp2f(S[kk * 2][1]);
            tpk[2] = (__bf16)__builtin_amdgcn_exp2f(S[kk * 2][2]);
            tpk[3] = (__bf16)__builtin_amdgcn_exp2f(S[kk * 2][3]);
            tpk[4] = (__bf16)__builtin_amdgcn_exp2f(S[kk * 2 + 1][0]);
            tpk[5] = (__bf16)__builtin_amdgcn_exp2f(S[kk * 2 + 1][1]);
            tpk[6] = (__bf16)__builtin_amdgcn_exp2f(S[kk * 2 + 1][2]);
            tpk[7] = (__bf16)__builtin_amdgcn_exp2f(S[kk * 2 + 1][3]);
            pb[kk] = tpk;
        }
        __builtin_amdgcn_s_setprio(1);
        lsum = __builtin_amdgcn_mfma_f32_16x16x32_bf16(ones, pb[0], lsum, 0, 0, 0);
        lsum = __builtin_amdgcn_mfma_f32_16x16x32_bf16(ones, pb[1], lsum, 0, 0, 0);
#pragma unroll
        for (int kk = 0; kk < 2; ++kk)
#pragma unroll
            for (int df = 0; df < 4; ++df) {
                const int row = df * 16 + r16;
                bf16x8 vb = *(const bf16x8*)((const char*)&sV[cur][0] + row * 128
                                             + ((kk * 64 + g * 16) ^ swzV));
                o[df] = __builtin_amdgcn_mfma_f32_16x16x32_bf16(vb, pb[kk], o[df], 0, 0, 0);
            }
        __builtin_amdgcn_s_setprio(0);
        __syncthreads();
    }

    const float inv = 1.f / lsum[0];
    const size_t token = (size_t)(bh >> 4) * 2048 + q0 + r16;
#pragma unroll
    for (int df = 0; df < 4; ++df) {
        bf16x4 ov = { (__bf16)(o[df][0] * inv), (__bf16)(o[df][1] * inv),
                      (__bf16)(o[df][2] * inv), (__bf16)(o[df][3] * inv) };
        *(bf16x4*)(O + token * 1024 + (bh & 15) * 64 + df * 16 + g * 4) = ov;
    }
}

// ---------------------------------------------------------------------------
extern "C" void kernel_launch(void* const* d_in, const int* in_sizes, int n_in,
                              void* d_out, int out_size, void* d_ws, size_t ws_size,
                              hipStream_t stream)
{
    const float* x     = (const float*)d_in[0];
    const float* Wqkv  = (const float*)d_in[1];
    const float* bqkv  = (const float*)d_in[2];
    const float* Wproj = (const float*)d_in[3];
    const float* bproj = (const float*)d_in[4];
    float* out = (float*)d_out;

    const size_t NX   = (size_t)4096 * 1024;
    const size_t NWQ  = (size_t)3072 * 1024;
    const size_t NWP  = (size_t)1024 * 1024;

    __bf16* xb  = (__bf16*)d_ws;
    __bf16* Wqb = xb  + NX;
    __bf16* Wpb = Wqb + NWQ;
    __bf16* Qs  = Wpb + NWP;           // (B,H,T,64), scaled 0.125*log2e
    __bf16* Ks  = Qs  + NX;            // (B,H,T,64)
    __bf16* Vt  = Ks  + NX;            // (B,H,64,T)
    __bf16* Os  = Vt  + NX;            // (B*T, C)

    cvt_all<<<dim3(2048), dim3(256), 0, stream>>>(x, Wqkv, Wproj, xb, Wqb, Wpb,
                                                  (int)NX, (int)NWQ, (int)NWP);
    gemm_qkv<<<dim3(24, 32), dim3(256), 0, stream>>>(xb, Wqb, bqkv, 1024, Qs, Ks, Vt);
    attn<<<dim3(32, 16, 2), dim3(256), 0, stream>>>(Qs, Ks, Vt, Os);
    gemm_proj<<<dim3(16, 32), dim3(256), 0, stream>>>(Os, Wpb, bproj, 1024, 1024, out);
}